// Round 1
// baseline (2507.431 us; speedup 1.0000x reference)
//
#include <hip/hip_runtime.h>
#include <math.h>

// Problem constants
#define R_  128
#define C_  256
#define E_  768
#define H_  12
#define DK_ 64
#define T_  (R_*C_)       // 32768 tokens
#define RSPLIT 4          // split-K over rows in attn kernel

// ---------------------------------------------------------------------------
// Projection GEMM: Y[t,e] = (sum_k X[t,k] * W[e,k] + b[e]) * scale
// M = T_ (or any multiple of 64), N = 768, K = 768.
// 64x64 block tile, BK=16, 256 threads, 4x4 per thread.
// LDS tiles stored transposed [k][m] with +4 pad so compute reads are
// 16B-aligned ds_read_b128 and conflict-free (row stride 68 floats = 272 B).
// ---------------------------------------------------------------------------
__global__ __launch_bounds__(256) void proj_kernel(
    const float* __restrict__ X, const float* __restrict__ W,
    const float* __restrict__ b, float* __restrict__ Y, float scale)
{
    __shared__ float As[16][68];
    __shared__ float Bs[16][68];
    const int tid = threadIdx.x;
    const int m0 = blockIdx.x * 64;
    const int n0 = blockIdx.y * 64;
    const int lr = tid >> 2;         // 0..63 (tile row)
    const int lc = (tid & 3) << 2;   // 0,4,8,12 (k offset)
    const int ty = tid >> 4;         // 0..15
    const int tx = tid & 15;         // 0..15

    float acc[4][4] = {};
    const float* xp = X + (size_t)(m0 + lr) * E_ + lc;
    const float* wp = W + (size_t)(n0 + lr) * E_ + lc;

    for (int k0 = 0; k0 < E_; k0 += 16) {
        float4 a4 = *(const float4*)(xp + k0);
        float4 b4 = *(const float4*)(wp + k0);
        As[lc+0][lr] = a4.x; As[lc+1][lr] = a4.y;
        As[lc+2][lr] = a4.z; As[lc+3][lr] = a4.w;
        Bs[lc+0][lr] = b4.x; Bs[lc+1][lr] = b4.y;
        Bs[lc+2][lr] = b4.z; Bs[lc+3][lr] = b4.w;
        __syncthreads();
        #pragma unroll
        for (int kk = 0; kk < 16; ++kk) {
            float4 av = *(const float4*)&As[kk][ty * 4];
            float4 bv = *(const float4*)&Bs[kk][tx * 4];
            float a[4] = {av.x, av.y, av.z, av.w};
            float bb[4] = {bv.x, bv.y, bv.z, bv.w};
            #pragma unroll
            for (int i = 0; i < 4; ++i)
                #pragma unroll
                for (int j = 0; j < 4; ++j)
                    acc[i][j] = fmaf(a[i], bb[j], acc[i][j]);
        }
        __syncthreads();
    }

    #pragma unroll
    for (int i = 0; i < 4; ++i) {
        float* yp = Y + (size_t)(m0 + ty * 4 + i) * E_ + n0 + tx * 4;
        #pragma unroll
        for (int j = 0; j < 4; ++j)
            yp[j] = (acc[i][j] + b[n0 + tx * 4 + j]) * scale;
    }
}

// ---------------------------------------------------------------------------
// Zero-init kernel (graph-capture-safe; d_out is poisoned 0xAA each call)
// ---------------------------------------------------------------------------
__global__ void zero_kernel(float* __restrict__ p, int n)
{
    int i = blockIdx.x * blockDim.x + threadIdx.x;
    if (i < n) p[i] = 0.0f;
}

// ---------------------------------------------------------------------------
// Pooled attention logits: logits[h,i,j] += sum_{r in chunk} sum_d q.k
// q,k layout: [t=r*C+i][e=h*64+d]. 64x64 (i,j) tile per block, split-K over
// r (RSPLIT chunks of 32 rows), fp32 atomicAdd epilogue into logits.
// ---------------------------------------------------------------------------
__global__ __launch_bounds__(256) void attn_kernel(
    const float* __restrict__ Q, const float* __restrict__ K,
    float* __restrict__ logits)
{
    __shared__ float Qs[64][68];   // [d][i]
    __shared__ float Ks[64][68];   // [d][j]
    const int tid = threadIdx.x;
    const int i0 = blockIdx.x * 64;
    const int j0 = blockIdx.y * 64;
    const int h  = blockIdx.z / RSPLIT;
    const int rc = blockIdx.z % RSPLIT;
    const int lr = tid >> 2;            // 0..63
    const int lc = (tid & 3) << 4;      // 0,16,32,48
    const int ty = tid >> 4;
    const int tx = tid & 15;

    float acc[4][4] = {};
    const int rbeg = rc * (R_ / RSPLIT);
    const int rend = rbeg + (R_ / RSPLIT);

    for (int r = rbeg; r < rend; ++r) {
        const float* qp = Q + ((size_t)(r * C_) + i0 + lr) * E_ + h * DK_ + lc;
        const float* kp = K + ((size_t)(r * C_) + j0 + lr) * E_ + h * DK_ + lc;
        #pragma unroll
        for (int u = 0; u < 4; ++u) {
            float4 a4 = *(const float4*)(qp + u * 4);
            float4 b4 = *(const float4*)(kp + u * 4);
            Qs[lc+u*4+0][lr] = a4.x; Qs[lc+u*4+1][lr] = a4.y;
            Qs[lc+u*4+2][lr] = a4.z; Qs[lc+u*4+3][lr] = a4.w;
            Ks[lc+u*4+0][lr] = b4.x; Ks[lc+u*4+1][lr] = b4.y;
            Ks[lc+u*4+2][lr] = b4.z; Ks[lc+u*4+3][lr] = b4.w;
        }
        __syncthreads();
        #pragma unroll 16
        for (int kk = 0; kk < 64; ++kk) {
            float4 av = *(const float4*)&Qs[kk][ty * 4];
            float4 bv = *(const float4*)&Ks[kk][tx * 4];
            float a[4] = {av.x, av.y, av.z, av.w};
            float bb[4] = {bv.x, bv.y, bv.z, bv.w};
            #pragma unroll
            for (int i = 0; i < 4; ++i)
                #pragma unroll
                for (int j = 0; j < 4; ++j)
                    acc[i][j] = fmaf(a[i], bb[j], acc[i][j]);
        }
        __syncthreads();
    }

    #pragma unroll
    for (int i = 0; i < 4; ++i) {
        float* lp = logits + ((size_t)h * C_ + i0 + ty * 4 + i) * C_ + j0 + tx * 4;
        #pragma unroll
        for (int j = 0; j < 4; ++j)
            atomicAdd(&lp[j], acc[i][j]);
    }
}

// ---------------------------------------------------------------------------
// In-place row softmax over last dim (C_=256). One 256-thread block per row.
// ---------------------------------------------------------------------------
__global__ __launch_bounds__(256) void softmax_kernel(float* __restrict__ P)
{
    const int row = blockIdx.x;            // 0 .. H_*C_-1
    float* p = P + (size_t)row * C_;
    const int t = threadIdx.x;
    const int wave = t >> 6, lane = t & 63;

    float val = p[t];
    float m = val;
    #pragma unroll
    for (int off = 32; off > 0; off >>= 1)
        m = fmaxf(m, __shfl_down(m, off, 64));
    __shared__ float redm[4];
    if (lane == 0) redm[wave] = m;
    __syncthreads();
    m = fmaxf(fmaxf(redm[0], redm[1]), fmaxf(redm[2], redm[3]));

    float e = expf(val - m);
    float s = e;
    #pragma unroll
    for (int off = 32; off > 0; off >>= 1)
        s += __shfl_down(s, off, 64);
    __shared__ float reds[4];
    if (lane == 0) reds[wave] = s;
    __syncthreads();
    s = reds[0] + reds[1] + reds[2] + reds[3];

    p[t] = e / s;
}

// ---------------------------------------------------------------------------
// Context: Cout[(r*C+i)*E + h*64 + d] = sum_j P[h,i,j] * V[(r*C+j)*E + h*64+d]
// 64(i) x 64(d) tile per block over K=256(j), BK=16.
// ---------------------------------------------------------------------------
__global__ __launch_bounds__(256) void ctx_kernel(
    const float* __restrict__ P, const float* __restrict__ V,
    float* __restrict__ Cout)
{
    __shared__ float Ps[16][68];   // [j][i]
    __shared__ float Vs[16][68];   // [j][d]
    const int tid = threadIdx.x;
    const int i0 = blockIdx.x * 64;
    const int r  = blockIdx.y;
    const int h  = blockIdx.z;
    const int ty = tid >> 4;
    const int tx = tid & 15;
    const int pr = tid >> 2;          // 0..63 (i)
    const int pc = (tid & 3) << 2;    // 0,4,8,12 (j)
    const int vj = tid >> 4;          // 0..15 (j)
    const int vd = (tid & 15) << 2;   // 0..60 (d)

    float acc[4][4] = {};
    for (int j0 = 0; j0 < C_; j0 += 16) {
        float4 p4 = *(const float4*)(P + ((size_t)h * C_ + i0 + pr) * C_ + j0 + pc);
        Ps[pc+0][pr] = p4.x; Ps[pc+1][pr] = p4.y;
        Ps[pc+2][pr] = p4.z; Ps[pc+3][pr] = p4.w;
        float4 v4 = *(const float4*)(V + ((size_t)(r * C_) + j0 + vj) * E_ + h * DK_ + vd);
        *(float4*)&Vs[vj][vd] = v4;
        __syncthreads();
        #pragma unroll
        for (int kk = 0; kk < 16; ++kk) {
            float4 av = *(const float4*)&Ps[kk][ty * 4];
            float4 bv = *(const float4*)&Vs[kk][tx * 4];
            float a[4] = {av.x, av.y, av.z, av.w};
            float bb[4] = {bv.x, bv.y, bv.z, bv.w};
            #pragma unroll
            for (int i = 0; i < 4; ++i)
                #pragma unroll
                for (int j = 0; j < 4; ++j)
                    acc[i][j] = fmaf(a[i], bb[j], acc[i][j]);
        }
        __syncthreads();
    }

    #pragma unroll
    for (int i = 0; i < 4; ++i) {
        float* cp = Cout + ((size_t)(r * C_) + i0 + ty * 4 + i) * E_ + h * DK_ + tx * 4;
        #pragma unroll
        for (int j = 0; j < 4; ++j)
            cp[j] = acc[i][j];
    }
}

// ---------------------------------------------------------------------------
extern "C" void kernel_launch(void* const* d_in, const int* in_sizes, int n_in,
                              void* d_out, int out_size, void* d_ws, size_t ws_size,
                              hipStream_t stream)
{
    (void)in_sizes; (void)n_in; (void)out_size; (void)ws_size;

    const float* x  = (const float*)d_in[0];
    const float* Wq = (const float*)d_in[1];
    const float* bq = (const float*)d_in[2];
    const float* Wk = (const float*)d_in[3];
    const float* bk = (const float*)d_in[4];
    const float* Wv = (const float*)d_in[5];
    const float* bv = (const float*)d_in[6];
    const float* Wo = (const float*)d_in[7];
    const float* bo = (const float*)d_in[8];

    float* out   = (float*)d_out;
    float* probs = out + (size_t)T_ * E_;   // logits then probs live here

    // Workspace: q | k | v  (context c reuses q's buffer — q dead after attn)
    float* q = (float*)d_ws;
    float* k = q + (size_t)T_ * E_;
    float* v = k + (size_t)T_ * E_;
    float* c = q;                            // alias: reuse q region

    const float scaling = 0.125f / sqrtf(128.0f);   // DK^-0.5 / sqrt(R)

    dim3 blk(256);
    // Q, K, V projections
    proj_kernel<<<dim3(T_/64, E_/64), blk, 0, stream>>>(x, Wq, bq, q, scaling);
    proj_kernel<<<dim3(T_/64, E_/64), blk, 0, stream>>>(x, Wk, bk, k, 1.0f);
    proj_kernel<<<dim3(T_/64, E_/64), blk, 0, stream>>>(x, Wv, bv, v, 1.0f);

    // Pooled attention logits (atomicAdd accumulation needs zeroed buffer)
    zero_kernel<<<dim3((H_*C_*C_ + 255)/256), blk, 0, stream>>>(probs, H_*C_*C_);
    attn_kernel<<<dim3(C_/64, C_/64, H_*RSPLIT), blk, 0, stream>>>(q, k, probs);

    // Shared softmax (in-place) -> probs is final output #2
    softmax_kernel<<<dim3(H_*C_), blk, 0, stream>>>(probs);

    // Context and output projection
    ctx_kernel<<<dim3(C_/64, R_, H_), blk, 0, stream>>>(probs, v, c);
    proj_kernel<<<dim3(T_/64, E_/64), blk, 0, stream>>>(c, Wo, bo, out, 1.0f);
}

// Round 3
// 884.478 us; speedup vs baseline: 2.8349x; 2.8349x over previous
//
#include <hip/hip_runtime.h>
#include <math.h>

// Problem constants
#define R_  128
#define C_  256
#define E_  768
#define H_  12
#define DK_ 64
#define T_  (R_*C_)       // 32768 tokens
#define RS_ 8             // split-K over rows in attn kernel
#define LP  40            // LDS tile row pitch in ushorts (32 + 8 pad, 80 B, 16B-aligned)

typedef __attribute__((ext_vector_type(8))) short          bf16x8;
typedef __attribute__((ext_vector_type(4))) float          f32x4;
typedef __attribute__((ext_vector_type(4))) unsigned short u16x4;
typedef __attribute__((ext_vector_type(8))) unsigned short u16x8;

struct HL { unsigned short h, l; };

// fp32 -> (hi, lo) bf16 split via truncation. hi+lo represents f with ~2^-16
// relative error; lo = f - hi is exact in fp32 (Sterbenz), then truncated.
__device__ __forceinline__ HL split2(float f) {
    HL o;
    unsigned int u = __float_as_uint(f);
    o.h = (unsigned short)(u >> 16);
    float r = f - __uint_as_float(u & 0xFFFF0000u);
    o.l = (unsigned short)(__float_as_uint(r) >> 16);
    return o;
}

// ---------------------------------------------------------------------------
// GEMM: Y[m,n] = (sum_k A[m,k]*B[n,k] + bias[n]) * scale
// M x 768 x 768, 128x128 block tile, BK=32, 256 threads (4 waves, 2x2 of
// 64x64 wave tiles), mfma_f32_16x16x32_bf16 with 3-term hi/lo split.
// AMODE 0: A fp32, split during staging.  AMODE 1: A pre-split (Ah, Al).
// OMODE 0: write split output (Yh, Yl).   OMODE 1: write fp32 Y.
// B is always fp32, split during staging.
// ---------------------------------------------------------------------------
template<int AMODE, int OMODE>
__global__ __launch_bounds__(256, 2) void gemm_kernel(
    const float* __restrict__ A32,
    const unsigned short* __restrict__ Ah, const unsigned short* __restrict__ Al,
    const float* __restrict__ B32, const float* __restrict__ bias, float scale,
    float* __restrict__ Y32, unsigned short* __restrict__ Yh, unsigned short* __restrict__ Yl)
{
    __shared__ __align__(16) unsigned short smem[20480];   // 40 KB
    unsigned short* AsH = smem;                // [128][LP]
    unsigned short* AsL = smem + 5120;
    unsigned short* BsH = smem + 10240;
    unsigned short* BsL = smem + 15360;

    const int tid  = threadIdx.x;
    const int m0   = blockIdx.x * 128;
    const int n0   = blockIdx.y * 128;
    const int wave = tid >> 6, lane = tid & 63;
    const int wm   = (wave & 1) * 64, wn = (wave >> 1) * 64;
    const int fr   = lane & 15;
    const int kq   = (lane >> 4) * 8;
    const int srow = tid >> 1;            // 0..127 (staging row)
    const int sk   = (tid & 1) * 16;      // staging k offset

    f32x4 acc[4][4] = {};

    for (int k0 = 0; k0 < E_; k0 += 32) {
        // ---- stage A tile (128 x 32) ----
        if constexpr (AMODE == 0) {
            const float* ap = A32 + (size_t)(m0 + srow) * E_ + k0 + sk;
            #pragma unroll
            for (int c = 0; c < 4; ++c) {
                float4 f = *(const float4*)(ap + 4 * c);
                u16x4 h4, l4;
                HL e0 = split2(f.x), e1 = split2(f.y), e2 = split2(f.z), e3 = split2(f.w);
                h4[0] = e0.h; h4[1] = e1.h; h4[2] = e2.h; h4[3] = e3.h;
                l4[0] = e0.l; l4[1] = e1.l; l4[2] = e2.l; l4[3] = e3.l;
                *(u16x4*)&AsH[srow * LP + sk + 4 * c] = h4;
                *(u16x4*)&AsL[srow * LP + sk + 4 * c] = l4;
            }
        } else {
            const unsigned short* aph = Ah + (size_t)(m0 + srow) * E_ + k0 + sk;
            const unsigned short* apl = Al + (size_t)(m0 + srow) * E_ + k0 + sk;
            *(u16x8*)&AsH[srow * LP + sk]     = *(const u16x8*)aph;
            *(u16x8*)&AsH[srow * LP + sk + 8] = *(const u16x8*)(aph + 8);
            *(u16x8*)&AsL[srow * LP + sk]     = *(const u16x8*)apl;
            *(u16x8*)&AsL[srow * LP + sk + 8] = *(const u16x8*)(apl + 8);
        }
        // ---- stage B tile (128 x 32), always fp32 convert ----
        {
            const float* bp = B32 + (size_t)(n0 + srow) * E_ + k0 + sk;
            #pragma unroll
            for (int c = 0; c < 4; ++c) {
                float4 f = *(const float4*)(bp + 4 * c);
                u16x4 h4, l4;
                HL e0 = split2(f.x), e1 = split2(f.y), e2 = split2(f.z), e3 = split2(f.w);
                h4[0] = e0.h; h4[1] = e1.h; h4[2] = e2.h; h4[3] = e3.h;
                l4[0] = e0.l; l4[1] = e1.l; l4[2] = e2.l; l4[3] = e3.l;
                *(u16x4*)&BsH[srow * LP + sk + 4 * c] = h4;
                *(u16x4*)&BsL[srow * LP + sk + 4 * c] = l4;
            }
        }
        __syncthreads();

        bf16x8 a_h[4], a_l[4], b_h[4], b_l[4];
        #pragma unroll
        for (int t = 0; t < 4; ++t) {
            a_h[t] = *(const bf16x8*)&AsH[(wm + t * 16 + fr) * LP + kq];
            a_l[t] = *(const bf16x8*)&AsL[(wm + t * 16 + fr) * LP + kq];
            b_h[t] = *(const bf16x8*)&BsH[(wn + t * 16 + fr) * LP + kq];
            b_l[t] = *(const bf16x8*)&BsL[(wn + t * 16 + fr) * LP + kq];
        }
        #pragma unroll
        for (int i = 0; i < 4; ++i)
            #pragma unroll
            for (int j = 0; j < 4; ++j) {
                acc[i][j] = __builtin_amdgcn_mfma_f32_16x16x32_bf16(a_h[i], b_h[j], acc[i][j], 0, 0, 0);
                acc[i][j] = __builtin_amdgcn_mfma_f32_16x16x32_bf16(a_h[i], b_l[j], acc[i][j], 0, 0, 0);
                acc[i][j] = __builtin_amdgcn_mfma_f32_16x16x32_bf16(a_l[i], b_h[j], acc[i][j], 0, 0, 0);
            }
        __syncthreads();
    }

    // ---- epilogue: per-wave LDS repack -> wide coalesced stores ----
    float* rep = (float*)smem + wave * 1024;   // [16][64] per wave
    const int mr = lane >> 2;
    const int nc = (lane & 3) * 16;
    #pragma unroll
    for (int ti = 0; ti < 4; ++ti) {
        __syncthreads();
        #pragma unroll
        for (int tj = 0; tj < 4; ++tj)
            #pragma unroll
            for (int r = 0; r < 4; ++r)
                rep[((lane >> 4) * 4 + r) * 64 + tj * 16 + fr] = acc[ti][tj][r];
        __syncthreads();
        float v[16];
        #pragma unroll
        for (int c = 0; c < 4; ++c)
            *(float4*)&v[4 * c] = *(const float4*)&rep[mr * 64 + nc + 4 * c];
        const int gm = m0 + wm + ti * 16 + mr;
        const int gn = n0 + wn + nc;
        if constexpr (OMODE == 1) {
            #pragma unroll
            for (int c = 0; c < 4; ++c) {
                float4 bv = *(const float4*)&bias[gn + 4 * c];
                float4 o;
                o.x = (v[4*c+0] + bv.x) * scale; o.y = (v[4*c+1] + bv.y) * scale;
                o.z = (v[4*c+2] + bv.z) * scale; o.w = (v[4*c+3] + bv.w) * scale;
                *(float4*)&Y32[(size_t)gm * E_ + gn + 4 * c] = o;
            }
        } else {
            unsigned short hh[16], ll[16];
            #pragma unroll
            for (int c = 0; c < 4; ++c) {
                float4 bv = *(const float4*)&bias[gn + 4 * c];
                HL e0 = split2((v[4*c+0] + bv.x) * scale);
                HL e1 = split2((v[4*c+1] + bv.y) * scale);
                HL e2 = split2((v[4*c+2] + bv.z) * scale);
                HL e3 = split2((v[4*c+3] + bv.w) * scale);
                hh[4*c+0] = e0.h; ll[4*c+0] = e0.l;
                hh[4*c+1] = e1.h; ll[4*c+1] = e1.l;
                hh[4*c+2] = e2.h; ll[4*c+2] = e2.l;
                hh[4*c+3] = e3.h; ll[4*c+3] = e3.l;
            }
            u16x8 H0, H1, L0, L1;
            #pragma unroll
            for (int j = 0; j < 8; ++j) { H0[j] = hh[j]; H1[j] = hh[8+j]; L0[j] = ll[j]; L1[j] = ll[8+j]; }
            *(u16x8*)&Yh[(size_t)gm * E_ + gn]     = H0;
            *(u16x8*)&Yh[(size_t)gm * E_ + gn + 8] = H1;
            *(u16x8*)&Yl[(size_t)gm * E_ + gn]     = L0;
            *(u16x8*)&Yl[(size_t)gm * E_ + gn + 8] = L1;
        }
    }
}

// ---------------------------------------------------------------------------
// Pooled attention logits, split-K over rows: part[rc,h,i,j] =
//   sum_{r in chunk rc} sum_d q[r,i,h,d] * k[r,j,h,d]
// 128x128 (i,j) tile per block, K-chunk = 16 rows * 64 d = 1024 (32 steps).
// Operands pre-split bf16 (qh,ql,kh,kl). fp32 partials, no atomics.
// ---------------------------------------------------------------------------
__global__ __launch_bounds__(256, 2) void attn_mfma(
    const unsigned short* __restrict__ Qh, const unsigned short* __restrict__ Ql,
    const unsigned short* __restrict__ Kh, const unsigned short* __restrict__ Kl,
    float* __restrict__ part)
{
    __shared__ __align__(16) unsigned short smem[20480];
    unsigned short* AsH = smem;
    unsigned short* AsL = smem + 5120;
    unsigned short* BsH = smem + 10240;
    unsigned short* BsL = smem + 15360;

    const int tid  = threadIdx.x;
    const int i0   = blockIdx.x * 128;
    const int j0   = blockIdx.y * 128;
    const int hz   = blockIdx.z;          // h * RS_ + rc
    const int h    = hz >> 3;
    const int rc   = hz & 7;
    const int wave = tid >> 6, lane = tid & 63;
    const int wm   = (wave & 1) * 64, wn = (wave >> 1) * 64;
    const int fr   = lane & 15;
    const int kq   = (lane >> 4) * 8;
    const int srow = tid >> 1;
    const int sk   = (tid & 1) * 16;

    f32x4 acc[4][4] = {};

    for (int s = 0; s < 32; ++s) {
        const int r  = rc * 16 + (s >> 1);
        const int d0 = (s & 1) * 32;
        const size_t qb = ((size_t)(r * C_) + i0 + srow) * E_ + h * DK_ + d0 + sk;
        const size_t kb = ((size_t)(r * C_) + j0 + srow) * E_ + h * DK_ + d0 + sk;
        *(u16x8*)&AsH[srow * LP + sk]     = *(const u16x8*)&Qh[qb];
        *(u16x8*)&AsH[srow * LP + sk + 8] = *(const u16x8*)&Qh[qb + 8];
        *(u16x8*)&AsL[srow * LP + sk]     = *(const u16x8*)&Ql[qb];
        *(u16x8*)&AsL[srow * LP + sk + 8] = *(const u16x8*)&Ql[qb + 8];
        *(u16x8*)&BsH[srow * LP + sk]     = *(const u16x8*)&Kh[kb];
        *(u16x8*)&BsH[srow * LP + sk + 8] = *(const u16x8*)&Kh[kb + 8];
        *(u16x8*)&BsL[srow * LP + sk]     = *(const u16x8*)&Kl[kb];
        *(u16x8*)&BsL[srow * LP + sk + 8] = *(const u16x8*)&Kl[kb + 8];
        __syncthreads();

        bf16x8 a_h[4], a_l[4], b_h[4], b_l[4];
        #pragma unroll
        for (int t = 0; t < 4; ++t) {
            a_h[t] = *(const bf16x8*)&AsH[(wm + t * 16 + fr) * LP + kq];
            a_l[t] = *(const bf16x8*)&AsL[(wm + t * 16 + fr) * LP + kq];
            b_h[t] = *(const bf16x8*)&BsH[(wn + t * 16 + fr) * LP + kq];
            b_l[t] = *(const bf16x8*)&BsL[(wn + t * 16 + fr) * LP + kq];
        }
        #pragma unroll
        for (int i = 0; i < 4; ++i)
            #pragma unroll
            for (int j = 0; j < 4; ++j) {
                acc[i][j] = __builtin_amdgcn_mfma_f32_16x16x32_bf16(a_h[i], b_h[j], acc[i][j], 0, 0, 0);
                acc[i][j] = __builtin_amdgcn_mfma_f32_16x16x32_bf16(a_h[i], b_l[j], acc[i][j], 0, 0, 0);
                acc[i][j] = __builtin_amdgcn_mfma_f32_16x16x32_bf16(a_l[i], b_h[j], acc[i][j], 0, 0, 0);
            }
        __syncthreads();
    }

    float* rep = (float*)smem + wave * 1024;
    const int mr = lane >> 2;
    const int nc = (lane & 3) * 16;
    #pragma unroll
    for (int ti = 0; ti < 4; ++ti) {
        __syncthreads();
        #pragma unroll
        for (int tj = 0; tj < 4; ++tj)
            #pragma unroll
            for (int r = 0; r < 4; ++r)
                rep[((lane >> 4) * 4 + r) * 64 + tj * 16 + fr] = acc[ti][tj][r];
        __syncthreads();
        const int gi = i0 + wm + ti * 16 + mr;
        const int gj = j0 + wn + nc;
        #pragma unroll
        for (int c = 0; c < 4; ++c) {
            float4 o = *(const float4*)&rep[mr * 64 + nc + 4 * c];
            *(float4*)&part[((size_t)(rc * H_ + h) * C_ + gi) * C_ + gj + 4 * c] = o;
        }
    }
}

// ---------------------------------------------------------------------------
// Reduce RS_ partials + row softmax + write fp32 probs and bf16 split.
// One 256-thread block per (h, i) row.
// ---------------------------------------------------------------------------
__global__ __launch_bounds__(256) void softmax_split(
    const float* __restrict__ part, float* __restrict__ probs,
    unsigned short* __restrict__ ph, unsigned short* __restrict__ pl)
{
    const int row = blockIdx.x;            // h * C_ + i
    const int j = threadIdx.x;
    const int wave = j >> 6, lane = j & 63;

    float s = 0.0f;
    #pragma unroll
    for (int rcn = 0; rcn < RS_; ++rcn)
        s += part[((size_t)rcn * H_ * C_ + row) * C_ + j];

    float m = s;
    #pragma unroll
    for (int off = 32; off > 0; off >>= 1)
        m = fmaxf(m, __shfl_down(m, off, 64));
    __shared__ float redm[4];
    if (lane == 0) redm[wave] = m;
    __syncthreads();
    m = fmaxf(fmaxf(redm[0], redm[1]), fmaxf(redm[2], redm[3]));

    float e = expf(s - m);
    float t = e;
    #pragma unroll
    for (int off = 32; off > 0; off >>= 1)
        t += __shfl_down(t, off, 64);
    __shared__ float reds[4];
    if (lane == 0) reds[wave] = t;
    __syncthreads();
    t = reds[0] + reds[1] + reds[2] + reds[3];

    float p = e / t;
    probs[(size_t)row * C_ + j] = p;
    HL sp = split2(p);
    ph[(size_t)row * C_ + j] = sp.h;
    pl[(size_t)row * C_ + j] = sp.l;
}

// ---------------------------------------------------------------------------
// Context: C[r*C+i, h*64+d] = sum_j P[h,i,j] * V[r*C+j, h*64+d], split output.
// Per (i-block, r, h): M=128(i), N=64(d), K=256(j), BK=32 -> 8 steps.
// V staged transposed into LDS ([d][j]).
// ---------------------------------------------------------------------------
__global__ __launch_bounds__(256, 2) void ctx_mfma(
    const unsigned short* __restrict__ Ph, const unsigned short* __restrict__ Pl,
    const unsigned short* __restrict__ Vh, const unsigned short* __restrict__ Vl,
    unsigned short* __restrict__ Ch, unsigned short* __restrict__ Cl)
{
    __shared__ __align__(16) unsigned short smem[15360];   // 30 KB
    unsigned short* PsH = smem;            // [128][LP]
    unsigned short* PsL = smem + 5120;
    unsigned short* VsH = smem + 10240;    // [64][LP]
    unsigned short* VsL = smem + 12800;

    const int tid  = threadIdx.x;
    const int i0   = blockIdx.x * 128;
    const int r    = blockIdx.y;
    const int h    = blockIdx.z;
    const int wave = tid >> 6, lane = tid & 63;
    const int wm   = (wave & 1) * 64, wn = (wave >> 1) * 32;
    const int fr   = lane & 15;
    const int kq   = (lane >> 4) * 8;
    const int srow = tid >> 1;
    const int sk   = (tid & 1) * 16;
    const int vjj  = tid & 31;
    const int vdg  = tid >> 5;             // 0..7

    f32x4 acc[4][2] = {};

    for (int s = 0; s < 8; ++s) {
        const int jb = s * 32;
        const size_t pb = ((size_t)(h * C_) + i0 + srow) * C_ + jb + sk;
        *(u16x8*)&PsH[srow * LP + sk]     = *(const u16x8*)&Ph[pb];
        *(u16x8*)&PsH[srow * LP + sk + 8] = *(const u16x8*)&Ph[pb + 8];
        *(u16x8*)&PsL[srow * LP + sk]     = *(const u16x8*)&Pl[pb];
        *(u16x8*)&PsL[srow * LP + sk + 8] = *(const u16x8*)&Pl[pb + 8];
        const size_t vb = ((size_t)(r * C_) + jb + vjj) * E_ + h * DK_ + vdg * 8;
        u16x8 v_h = *(const u16x8*)&Vh[vb];
        u16x8 v_l = *(const u16x8*)&Vl[vb];
        #pragma unroll
        for (int u = 0; u < 8; ++u) {
            VsH[(vdg * 8 + u) * LP + vjj] = v_h[u];
            VsL[(vdg * 8 + u) * LP + vjj] = v_l[u];
        }
        __syncthreads();

        bf16x8 p_h[4], p_l[4], w_h[2], w_l[2];
        #pragma unroll
        for (int t = 0; t < 4; ++t) {
            p_h[t] = *(const bf16x8*)&PsH[(wm + t * 16 + fr) * LP + kq];
            p_l[t] = *(const bf16x8*)&PsL[(wm + t * 16 + fr) * LP + kq];
        }
        #pragma unroll
        for (int t = 0; t < 2; ++t) {
            w_h[t] = *(const bf16x8*)&VsH[(wn + t * 16 + fr) * LP + kq];
            w_l[t] = *(const bf16x8*)&VsL[(wn + t * 16 + fr) * LP + kq];
        }
        #pragma unroll
        for (int i = 0; i < 4; ++i)
            #pragma unroll
            for (int j = 0; j < 2; ++j) {
                acc[i][j] = __builtin_amdgcn_mfma_f32_16x16x32_bf16(p_h[i], w_h[j], acc[i][j], 0, 0, 0);
                acc[i][j] = __builtin_amdgcn_mfma_f32_16x16x32_bf16(p_h[i], w_l[j], acc[i][j], 0, 0, 0);
                acc[i][j] = __builtin_amdgcn_mfma_f32_16x16x32_bf16(p_l[i], w_h[j], acc[i][j], 0, 0, 0);
            }
        __syncthreads();
    }

    float* rep = (float*)smem + wave * 512;   // [16][32] per wave
    const int mr = lane >> 2;
    const int nc = (lane & 3) * 8;
    #pragma unroll
    for (int ti = 0; ti < 4; ++ti) {
        __syncthreads();
        #pragma unroll
        for (int tj = 0; tj < 2; ++tj)
            #pragma unroll
            for (int rr = 0; rr < 4; ++rr)
                rep[((lane >> 4) * 4 + rr) * 32 + tj * 16 + fr] = acc[ti][tj][rr];
        __syncthreads();
        float v[8];
        *(float4*)&v[0] = *(const float4*)&rep[mr * 32 + nc];
        *(float4*)&v[4] = *(const float4*)&rep[mr * 32 + nc + 4];
        const int gm = r * C_ + i0 + wm + ti * 16 + mr;
        const int gn = h * DK_ + wn + nc;
        u16x8 H8, L8;
        #pragma unroll
        for (int jj = 0; jj < 8; ++jj) { HL e = split2(v[jj]); H8[jj] = e.h; L8[jj] = e.l; }
        *(u16x8*)&Ch[(size_t)gm * E_ + gn] = H8;
        *(u16x8*)&Cl[(size_t)gm * E_ + gn] = L8;
    }
}

// ---------------------------------------------------------------------------
extern "C" void kernel_launch(void* const* d_in, const int* in_sizes, int n_in,
                              void* d_out, int out_size, void* d_ws, size_t ws_size,
                              hipStream_t stream)
{
    (void)in_sizes; (void)n_in; (void)out_size; (void)ws_size;

    const float* x  = (const float*)d_in[0];
    const float* Wq = (const float*)d_in[1];
    const float* bq = (const float*)d_in[2];
    const float* Wk = (const float*)d_in[3];
    const float* bk = (const float*)d_in[4];
    const float* Wv = (const float*)d_in[5];
    const float* bv = (const float*)d_in[6];
    const float* Wo = (const float*)d_in[7];
    const float* bo = (const float*)d_in[8];

    float* out   = (float*)d_out;
    float* probs = out + (size_t)T_ * E_;
    float* part  = out;                     // scratch: out region free until last GEMM

    // ws: 6 planar bf16 buffers of T_*E_ ushorts = 302 MB total (same as R0)
    const size_t QN = (size_t)T_ * E_;
    unsigned short* qh = (unsigned short*)d_ws;
    unsigned short* ql = qh + QN;
    unsigned short* kh = ql + QN;
    unsigned short* kl = kh + QN;
    unsigned short* vh = kl + QN;
    unsigned short* vl = vh + QN;
    unsigned short* ph = kh;                 // reuse k region (dead after attn)
    unsigned short* pl = kh + (size_t)H_ * C_ * C_;
    unsigned short* ch = qh;                 // reuse q region (dead after attn)
    unsigned short* cl = ql;

    const float scaling = 0.125f / sqrtf(128.0f);   // DK^-0.5 / sqrt(R)

    dim3 blk(256);
    gemm_kernel<0, 0><<<dim3(T_ / 128, E_ / 128), blk, 0, stream>>>(
        x, nullptr, nullptr, Wq, bq, scaling, nullptr, qh, ql);
    gemm_kernel<0, 0><<<dim3(T_ / 128, E_ / 128), blk, 0, stream>>>(
        x, nullptr, nullptr, Wk, bk, 1.0f, nullptr, kh, kl);
    gemm_kernel<0, 0><<<dim3(T_ / 128, E_ / 128), blk, 0, stream>>>(
        x, nullptr, nullptr, Wv, bv, 1.0f, nullptr, vh, vl);

    attn_mfma<<<dim3(C_ / 128, C_ / 128, H_ * RS_), blk, 0, stream>>>(qh, ql, kh, kl, part);
    softmax_split<<<dim3(H_ * C_), blk, 0, stream>>>(part, probs, ph, pl);
    ctx_mfma<<<dim3(C_ / 128, R_, H_), blk, 0, stream>>>(ph, pl, vh, vl, ch, cl);

    gemm_kernel<1, 1><<<dim3(T_ / 128, E_ / 128), blk, 0, stream>>>(
        nullptr, ch, cl, Wo, bo, 1.0f, out, nullptr, nullptr);
}